// Round 9
// baseline (581.671 us; speedup 1.0000x reference)
//
#include <hip/hip_runtime.h>

// QuantumQLSTM on MI355X — R20: angle-addition restructure. Gate cos moves OFF
// the serial chain: cos(zx+zh) = cos(zx)cos(zh) - sin(zx)sin(zh).
//  - zx_kernel precomputes cos/sin of the x-projection angles (two arrays).
//  - matvec tail lanes (12 of them) compute {cos,sin}(zh) once per step
//    (fract + v_cos + v_sin on lanes 31/63 of waves 0-5) into the zh LDS slot.
//  - gate phase: 6x (mul+fma) pure VALU — zero trans, zero add.
// rec structure otherwise = R19 (half-wave matvec, DPP xor1, 2 barriers).
//
// R19 post-mortem: rec 339->321, matched prediction. Chain = sum of segments;
// this removes the 12-trans gate segment (~30-50cy/step issue+latency).
// Predicted: rec ~300-312, total ~558-572. absmax unchanged (exact identity).
//
// History: R1 4250 -> ... -> R11 632 (rec 354) -> R13 643 (NEUTRAL) ->
// R14 600 (rec 339) -> R16 600 (nt: null) -> R18 891 (fusion REGRESSION) ->
// R19 578.6 (rec 321: half-wave matvec + revolutions) -> R20.

#define T_DIM 512
#define B_DIM 256
#define D_DIM 256
#define H_DIM 256
#define DH    512   // D + H
#define NG    16    // 4 gates * NQ(4)
#define XPAD  68    // Xc/Wc LDS row stride (floats): 16B-aligned, 2-way max
#define INV2PI 0.15915494309189535f

typedef float f32x4 __attribute__((ext_vector_type(4)));  // clang-native 16B vec

#if __has_builtin(__builtin_amdgcn_fractf) && __has_builtin(__builtin_amdgcn_cosf) && __has_builtin(__builtin_amdgcn_sinf)
#define TRIG_REV 1
#else
#define TRIG_REV 0
#endif

__device__ __forceinline__ float fast_sigmoid(float x) {
    return 1.0f / (1.0f + __expf(-x));
}
__device__ __forceinline__ float fast_tanh(float x) {
    // |x| <= ~2.1 here (|C| <= 0.557/(1-0.731)); exp safe
    float e = __expf(2.0f * x);
    return (e - 1.0f) / (e + 1.0f);
}
// x + dpp_mov(x): one reduction level, VALU pipe.
template <int CTRL, int RM, int BM, bool BC>
__device__ __forceinline__ float dadd(float x) {
    return x + __int_as_float(
        __builtin_amdgcn_update_dpp(0, __float_as_int(x), CTRL, RM, BM, BC));
}
// 32-lane-group sum: lane31 = sum(lanes 0..31), lane63 = sum(lanes 32..63).
__device__ __forceinline__ float rsum32(float x) {
    x = dadd<0x111, 0xf, 0xf, true >(x);   // row_shr:1
    x = dadd<0x112, 0xf, 0xf, true >(x);   // row_shr:2
    x = dadd<0x114, 0xf, 0xf, true >(x);   // row_shr:4
    x = dadd<0x118, 0xf, 0xf, true >(x);   // row_shr:8
    x = dadd<0x142, 0xa, 0xf, false>(x);   // row_bcast:15 -> lanes 31, 63
    return x;
}
// lane^1 exchange on the VALU pipe: quad_perm [1,0,3,2]
__device__ __forceinline__ float dpp_xor1(float x) {
    return __int_as_float(
        __builtin_amdgcn_update_dpp(0, __float_as_int(x), 0xB1, 0xf, 0xf, true));
}
// Barrier draining ONLY the LDS pipe (no vmcnt): global ops float across steps.
__device__ __forceinline__ void lds_barrier() {
    __asm__ volatile("s_waitcnt lgkmcnt(0)\n\ts_barrier" ::: "memory");
}

// -------------------- zx precompute (R14 4x4 register tiling; R20: outputs
// are cos/sin of the angle b_q + phi_q + x.Wx[q,:], two arrays)
__global__ __launch_bounds__(256) void zx_kernel(
    const float* __restrict__ x,
    const float* __restrict__ Wf, const float* __restrict__ Wi,
    const float* __restrict__ Wu, const float* __restrict__ Wo,
    const float* __restrict__ bf, const float* __restrict__ bi,
    const float* __restrict__ bu, const float* __restrict__ bo,
    const float* __restrict__ phf, const float* __restrict__ phi,
    const float* __restrict__ phu, const float* __restrict__ pho,
    float* __restrict__ zxc, float* __restrict__ zxs)
{
    __shared__ float Xc[256][XPAD];
    __shared__ float Wc[NG][XPAD];
    const int tid = threadIdx.x;
    const int rt  = tid >> 2;           // 0..63
    const int qt  = tid & 3;            // gate index 0..3

    const float* bv = (qt == 0) ? bf : (qt == 1) ? bi : (qt == 2) ? bu : bo;
    const float* pv = (qt == 0) ? phf : (qt == 1) ? phi : (qt == 2) ? phu : pho;
    float acc[4][4];
    #pragma unroll
    for (int j = 0; j < 4; ++j) {
        const float bj = bv[j] + pv[j];
        acc[0][j] = bj; acc[1][j] = bj; acc[2][j] = bj; acc[3][j] = bj;
    }

    const long base = (long)blockIdx.x * 256 * D_DIM;

    for (int c = 0; c < 4; ++c) {                 // k-chunk of 64
        const int k0 = c * 64;
        #pragma unroll
        for (int it = 0; it < 16; ++it) {
            const int e = tid + it * 256;
            const int row = e >> 4, col4 = (e & 15) * 4;
            *(float4*)&Xc[row][col4] =
                *(const float4*)(x + base + (long)row * D_DIM + k0 + col4);
        }
        {
            const int q16 = tid >> 4, col4 = (tid & 15) * 4;
            const int g = q16 >> 2, qj = q16 & 3;
            const float* W = (g == 0) ? Wf : (g == 1) ? Wi : (g == 2) ? Wu : Wo;
            *(float4*)&Wc[q16][col4] = *(const float4*)(W + qj * DH + k0 + col4);
        }
        __syncthreads();

        #pragma unroll 4
        for (int kk = 0; kk < 16; ++kk) {
            const int k4 = kk * 4;
            float4 xv0 = *(float4*)&Xc[rt][k4];
            float4 xv1 = *(float4*)&Xc[rt +  64][k4];
            float4 xv2 = *(float4*)&Xc[rt + 128][k4];
            float4 xv3 = *(float4*)&Xc[rt + 192][k4];
            float4 wv0 = *(float4*)&Wc[4 * qt + 0][k4];
            float4 wv1 = *(float4*)&Wc[4 * qt + 1][k4];
            float4 wv2 = *(float4*)&Wc[4 * qt + 2][k4];
            float4 wv3 = *(float4*)&Wc[4 * qt + 3][k4];
            #pragma unroll
            for (int i = 0; i < 4; ++i) {
                const float4 xv = (i == 0) ? xv0 : (i == 1) ? xv1 : (i == 2) ? xv2 : xv3;
                acc[i][0] = fmaf(xv.x, wv0.x, fmaf(xv.y, wv0.y, fmaf(xv.z, wv0.z, fmaf(xv.w, wv0.w, acc[i][0]))));
                acc[i][1] = fmaf(xv.x, wv1.x, fmaf(xv.y, wv1.y, fmaf(xv.z, wv1.z, fmaf(xv.w, wv1.w, acc[i][1]))));
                acc[i][2] = fmaf(xv.x, wv2.x, fmaf(xv.y, wv2.y, fmaf(xv.z, wv2.z, fmaf(xv.w, wv2.w, acc[i][2]))));
                acc[i][3] = fmaf(xv.x, wv3.x, fmaf(xv.y, wv3.y, fmaf(xv.z, wv3.z, fmaf(xv.w, wv3.w, acc[i][3]))));
            }
        }
        __syncthreads();
    }

    const long orow = (long)blockIdx.x * 256;
    #pragma unroll
    for (int i = 0; i < 4; ++i) {
        const long off = (orow + rt + 64 * i) * NG + qt * 4;
        *(float4*)&zxc[off] = make_float4(__cosf(acc[i][0]), __cosf(acc[i][1]),
                                          __cosf(acc[i][2]), __cosf(acc[i][3]));
        *(float4*)&zxs[off] = make_float4(__sinf(acc[i][0]), __sinf(acc[i][1]),
                                          __sinf(acc[i][2]), __sinf(acc[i][3]));
    }
}

// -------------------- sequential core: ONE block, 512 threads (8 waves)
// R20: matvec tail lanes compute {cos,sin}(zh) into zh_cs; gates are pure fma.
__global__ __launch_bounds__(512) void rec_kernel(
    const float* __restrict__ Wf, const float* __restrict__ Wi,
    const float* __restrict__ Wu, const float* __restrict__ Wo,
    const float* __restrict__ zxc, const float* __restrict__ zxs,
    float* __restrict__ hv_tab,   // [T][H]; hv_tab[-H..-1] is a scratch pad row
    float* __restrict__ c_fin)    // [H]
{
    __shared__ float Hbuf[2][H_DIM];       // double-buffered Hv
    __shared__ __align__(16) float zh_cs[2][12];  // [half][{CZ,SZ} x 6 cols]
    const int tid  = threadIdx.x;          // 0..511
    const int lane = tid & 63;
    const int wv   = tid >> 6;             // wave 0..7
    const int h    = tid >> 1;             // 0..255
    const int half = tid & 1;              // 0: f,i   1: u,o
    const int l31  = lane & 31;

    // matvec weights: col = 2*wv + (lane>>5); scaled to revolutions.
    float4 W0 = make_float4(0,0,0,0), W1 = W0;
    if (wv < 6) {
        const int c = 2 * wv + (lane >> 5);
        const int g = c / 3, j = c % 3 + 1;
        const float* Wg = (g == 0) ? Wf : (g == 1) ? Wi : (g == 2) ? Wu : Wo;
        W0 = *(const float4*)(Wg + j * DH + 256 + 4 * l31);
        W1 = *(const float4*)(Wg + j * DH + 256 + 128 + 4 * l31);
        W0.x *= INV2PI; W0.y *= INV2PI; W0.z *= INV2PI; W0.w *= INV2PI;
        W1.x *= INV2PI; W1.y *= INV2PI; W1.z *= INV2PI; W1.w *= INV2PI;
    }

    float C = 0.0f, Hprev = 0.0f;
    if (tid < H_DIM) Hbuf[1][tid] = 0.0f;  // Hv[-1] = 0
    __syncthreads();

    // zx cos/sin register double-buffer (depth 2)
    float4 ac0, ac1, as0, as1;             // t even
    float4 bc0, bc1, bs0, bs1;             // t odd
    {
        const float4* pc0 = (const float4*)(zxc + (long)h * NG) + half * 2;
        const float4* ps0 = (const float4*)(zxs + (long)h * NG) + half * 2;
        const float4* pc1 = (const float4*)(zxc + ((long)B_DIM + h) * NG) + half * 2;
        const float4* ps1 = (const float4*)(zxs + ((long)B_DIM + h) * NG) + half * 2;
        ac0 = pc0[0]; ac1 = pc0[1]; as0 = ps0[0]; as1 = ps0[1];
        bc0 = pc1[0]; bc1 = pc1[1]; bs0 = ps1[0]; bs1 = ps1[1];
    }

    auto step = [&](int t, float4& zc0, float4& zc1, float4& zs0, float4& zs1) {
        // early-issue global store of Hv[t-1] (half1 lanes; acks float)
        if (half) hv_tab[(long)(t - 1) * H_DIM + h] = Hprev;

        // ---- matvec: waves 0..5, one column per half-wave; tail does trig
        if (wv < 6) {
            const float4 H0 = *(const float4*)&Hbuf[(t + 1) & 1][4 * l31];
            const float4 H1 = *(const float4*)&Hbuf[(t + 1) & 1][4 * l31 + 128];
            float p0 = fmaf(W0.x, H0.x, fmaf(W0.y, H0.y, fmaf(W0.z, H0.z, W0.w * H0.w)));
            float p1 = fmaf(W1.x, H1.x, fmaf(W1.y, H1.y, fmaf(W1.z, H1.z, W1.w * H1.w)));
            float p  = rsum32(p0 + p1);      // zh in revolutions
            if (l31 == 31) {                 // lanes 31 (col 2w) and 63 (col 2w+1)
                const int c = 2 * wv + (lane >> 5);
                float CZ, SZ;
#if TRIG_REV
                const float fr = __builtin_amdgcn_fractf(p);
                CZ = __builtin_amdgcn_cosf(fr);
                SZ = __builtin_amdgcn_sinf(fr);
#else
                const float ang = p * 6.283185307179586f;
                CZ = __cosf(ang);
                SZ = __sinf(ang);
#endif
                *(float2*)&zh_cs[c / 6][2 * (c % 6)] = make_float2(CZ, SZ);
            }
        }
        lds_barrier();                      // zh_cs + Hbuf(t-1) reads done below

        // ---- gates: pure fma via angle addition (half0: f,i ; half1: u,o)
        const float4 Z0 = *(const float4*)&zh_cs[half][0];  // CZ0,SZ0,CZ1,SZ1
        const float4 Z1 = *(const float4*)&zh_cs[half][4];  // CZ2,SZ2,CZ3,SZ3
        const float4 Z2 = *(const float4*)&zh_cs[half][8];  // CZ4,SZ4,CZ5,SZ5
        const float cA1 = zc0.y * Z0.x - zs0.y * Z0.y;
        const float cA2 = zc0.z * Z0.z - zs0.z * Z0.w;
        const float cA3 = zc0.w * Z1.x - zs0.w * Z1.y;
        const float cB1 = zc1.y * Z1.z - zs1.y * Z1.w;
        const float cB2 = zc1.z * Z2.x - zs1.z * Z2.y;
        const float cB3 = zc1.w * Z2.z - zs1.w * Z2.w;
        const float pA = cA1 * cA2 * cA3, pB = cB1 * cB2 * cB3;
        float gA, gB;
        if (half == 0) { gA = fast_sigmoid(pA); gB = fast_sigmoid(pB); }   // f, i
        else           { gA = fast_tanh(pA);    gB = fast_sigmoid(pB); }   // g, o
        const float oA = dpp_xor1(gA);        // partner's first value (VALU)
        const float oB = dpp_xor1(gB);        // partner's second value
        const float f_ = half ? oA : gA;
        const float i_ = half ? oB : gB;
        const float g_ = half ? gA : oA;
        const float o_ = half ? gB : oB;

        // prefetch zx cos/sin [t+2] (floats across steps)
        {
            const int tp = (t + 2 < T_DIM) ? (t + 2) : t;
            const float4* pc = (const float4*)(zxc + ((long)tp * B_DIM + h) * NG) + half * 2;
            const float4* ps = (const float4*)(zxs + ((long)tp * B_DIM + h) * NG) + half * 2;
            zc0 = pc[0]; zc1 = pc[1];
            zs0 = ps[0]; zs1 = ps[1];
        }

        C = fmaf(f_, C, i_ * g_);             // both halves redundant, bit-identical
        const float Hnew = o_ * fast_tanh(C);
        if (half == 0) Hbuf[t & 1][h] = Hnew;
        Hprev = Hnew;
        lds_barrier();                        // Hbuf(t) + zh_cs WAR for next step
    };

    for (int t = 0; t < T_DIM; t += 2) {
        step(t,     ac0, ac1, as0, as1);
        step(t + 1, bc0, bc1, bs0, bs1);
    }

    if (half) {
        hv_tab[(long)(T_DIM - 1) * H_DIM + h] = Hprev;
        c_fin[h] = C;
    }
}

// -------------------- broadcast: out[t,b,:] = Hv[t,:]; tails hx=Hv[511], cx=Cfin
__global__ __launch_bounds__(256) void bc_kernel(
    const float* __restrict__ hv_tab, const float* __restrict__ c_fin,
    float* __restrict__ out)
{
    const int blk  = blockIdx.x;
    const int w    = threadIdx.x >> 6;
    const int lane = threadIdx.x & 63;

    const float* src;
    long base;
    int rbase;
    if (blk < 4 * T_DIM) {
        const int t = blk >> 2;
        rbase = (blk & 3) * 64;
        src = hv_tab + (long)t * H_DIM;
        base = (long)t * (B_DIM * H_DIM);
    } else {
        const int k = blk - 4 * T_DIM;        // 0..7
        rbase = (k & 3) * 64;
        src = (k < 4) ? (hv_tab + (long)(T_DIM - 1) * H_DIM) : c_fin;
        base = (long)T_DIM * (B_DIM * H_DIM) + (k < 4 ? 0 : (long)B_DIM * H_DIM);
    }
    const f32x4 v = ((const f32x4*)src)[lane];
    #pragma unroll
    for (int it = 0; it < 16; ++it) {
        const int row = rbase + w + 4 * it;
        __builtin_nontemporal_store(
            v, (f32x4*)(out + base + (long)row * H_DIM) + lane);
    }
}

extern "C" void kernel_launch(void* const* d_in, const int* in_sizes, int n_in,
                              void* d_out, int out_size, void* d_ws, size_t ws_size,
                              hipStream_t stream) {
    (void)in_sizes; (void)n_in; (void)out_size; (void)ws_size;
    const float* x   = (const float*)d_in[0];
    const float* Wf  = (const float*)d_in[1];
    const float* bf  = (const float*)d_in[2];
    const float* phf = (const float*)d_in[3];
    const float* Wi  = (const float*)d_in[4];
    const float* bi  = (const float*)d_in[5];
    const float* phi = (const float*)d_in[6];
    const float* Wu  = (const float*)d_in[7];
    const float* bu  = (const float*)d_in[8];
    const float* phu = (const float*)d_in[9];
    const float* Wo  = (const float*)d_in[10];
    const float* bo  = (const float*)d_in[11];
    const float* pho = (const float*)d_in[12];

    float* zxc    = (float*)d_ws;                          // T*B*16 f = 8.39 MB
    float* zxs    = zxc + (size_t)T_DIM * B_DIM * NG;      // T*B*16 f = 8.39 MB
    float* hv_pad = zxs + (size_t)T_DIM * B_DIM * NG;      // 256 f scratch (t=0 store)
    float* hv_tab = hv_pad + H_DIM;                        // T*H f = 512 KB
    float* c_fin  = hv_tab + (size_t)T_DIM * H_DIM;        // H f = 1 KB

    zx_kernel<<<T_DIM, 256, 0, stream>>>(
        x, Wf, Wi, Wu, Wo, bf, bi, bu, bo, phf, phi, phu, pho, zxc, zxs);

    rec_kernel<<<1, 512, 0, stream>>>(
        Wf, Wi, Wu, Wo, zxc, zxs, hv_tab, c_fin);

    bc_kernel<<<4 * T_DIM + 8, 256, 0, stream>>>(hv_tab, c_fin, (float*)d_out);
}